// Round 10
// baseline (235.753 us; speedup 1.0000x reference)
//
#include <hip/hip_runtime.h>
#include <hip/hip_bf16.h>

#define A_TOT 8400
#define NB 32
#define NG 16
#define NC 80

#define K1_GX 33                  // ceil(8400/256)
#define SEG   (K1_GX * 256)       // 8448 compaction slots per batch
#define NWAVE (K1_GX * NB * 4)    // per-wave conf partials

#define L2E 1.44269504088896340736f
#define LN2 0.69314718055994530942f

// ---------- fast native transcendentals ----------
__device__ inline float fexp2(float x) { return __builtin_amdgcn_exp2f(x); }
__device__ inline float flog2(float x) { return __builtin_amdgcn_logf(x); }
__device__ inline float frcp(float x)  { return __builtin_amdgcn_rcpf(x); }
__device__ inline float fsqrtf_(float x) { return __builtin_amdgcn_sqrtf(x); }

__device__ inline float iou_cxcywh(float acx, float acy, float aw, float ah,
                                   float bcx, float bcy, float bw, float bh) {
    float tlx = fmaxf(acx - aw * 0.5f, bcx - bw * 0.5f);
    float tly = fmaxf(acy - ah * 0.5f, bcy - bh * 0.5f);
    float brx = fminf(acx + aw * 0.5f, bcx + bw * 0.5f);
    float bry = fminf(acy + ah * 0.5f, bcy + bh * 0.5f);
    float w = fmaxf(brx - tlx, 0.0f);
    float h = fmaxf(bry - tly, 0.0f);
    float inter = w * h;
    return inter / (aw * ah + bw * bh - inter + 1e-16f);
}

// d = logp - log1mp for class logit x and conf-sigmoid sc
__device__ inline float dval_of(float x, float sc) {
    float u = fexp2(-x * L2E);
    float sx = frcp(1.0f + u);
    float pr = fsqrtf_(sx * sc);
    float lp  = fmaxf(LN2 * flog2(fmaxf(pr, 1e-12f)), -100.0f);
    float l1p = fmaxf(LN2 * flog2(fmaxf(1.0f - pr, 1e-12f)), -100.0f);
    return lp - l1p;
}

__device__ inline unsigned long long umax64(unsigned long long a, unsigned long long b) {
    return a > b ? a : b;
}
__device__ inline unsigned long long umin64(unsigned long long a, unsigned long long b) {
    return a < b ? a : b;
}

// resolve anchor index -> level base / hw / HW / W / stride
__device__ inline const float* lvl_base(int a, int b, const float* p8, const float* p16,
                                        const float* p32, int& hw, int& HW, int& W, float& s) {
    if (a < 6400) { hw = a;        HW = 6400; W = 80; s = 8.0f;  return p8  + (size_t)b * 85 * 6400; }
    if (a < 8000) { hw = a - 6400; HW = 1600; W = 40; s = 16.0f; return p16 + (size_t)b * 85 * 1600; }
    { hw = a - 8000; HW = 400; W = 20; s = 32.0f; return p32 + (size_t)b * 85 * 400; }
}

// ---------- kernel 1: decode + masks; per-block-segment union compaction ----------
// pbox_c/rec_c/cmp are SLOT-indexed (slot = b*SEG + bx*256 + local), union only.
// rec_c = {umask bits, sigmoid(conf), sum log1mp, conf logit}. cnt[b*33+bx] = count.
__global__ __launch_bounds__(256) void k1_decode(
    const float* __restrict__ p8, const float* __restrict__ p16, const float* __restrict__ p32,
    const float* __restrict__ gtb,
    float4* __restrict__ pbox_c, float4* __restrict__ rec_c,
    int* __restrict__ cmp, int* __restrict__ cnt, float* __restrict__ part) {
    __shared__ int lcnt;
    int b = blockIdx.y;
    int tid = threadIdx.x;
    int a = blockIdx.x * 256 + tid;
    if (tid == 0) lcnt = 0;
    __syncthreads();

    float bce0_conf = 0.0f;
    if (a < A_TOT) {
        int hw, HW, W;
        float s;
        const float* base = lvl_base(a, b, p8, p16, p32, hw, HW, W, s);

        float cf = base[4 * HW + hw];
        float uc = fexp2(-cf * L2E);
        float suc = 1.0f + uc;
        float sc = frcp(suc);
        bce0_conf = cf + LN2 * flog2(suc);    // bce0(conf)

        int gx = hw % W, gy = hw / W;
        float xc = ((float)gx + 0.5f) * s;
        float yc = ((float)gy + 0.5f) * s;
        unsigned m = 0;
        bool uni = false;
        float r = 2.5f * s;
#pragma unroll 4
        for (int g = 0; g < NG; g++) {
            float gcx = gtb[(b * NG + g) * 4 + 0];
            float gcy = gtb[(b * NG + g) * 4 + 1];
            float gw  = gtb[(b * NG + g) * 4 + 2];
            float gh  = gtb[(b * NG + g) * 4 + 3];
            bool ib = (xc > gcx - gw * 0.5f) && (gcx + gw * 0.5f > xc) &&
                      (yc > gcy - gh * 0.5f) && (gcy + gh * 0.5f > yc);
            bool im = (xc > gcx - r) && (gcx + r > xc) &&
                      (yc > gcy - r) && (gcy + r > yc);
            uni |= (ib || im);
            if (ib && im) m |= (1u << g);
        }
        if (uni) {
            m |= (1u << 16);
            int myslot = atomicAdd(&lcnt, 1);
            // box decode (union only)
            float tx = base[hw], ty = base[HW + hw];
            float tw = base[2 * HW + hw], th = base[3 * HW + hw];
            float pcx = (tx + (float)gx) * s;
            float pcy = (ty + (float)gy) * s;
            float pw = fexp2(tw * L2E) * s;
            float ph = fexp2(th * L2E) * s;
            // class-sum (union only); predicated but lanes stay clustered
            float suml1p = 0.0f;
            const float* cbase = base + 5 * HW + hw;
#pragma unroll
            for (int cc = 0; cc < NC; cc += 20) {
                float x[20];
#pragma unroll
                for (int j = 0; j < 20; j++) x[j] = cbase[(cc + j) * HW];
#pragma unroll
                for (int j = 0; j < 20; j++) {
                    float u = fexp2(-x[j] * L2E);
                    float pr = fsqrtf_(frcp(1.0f + u) * sc);
                    suml1p += fmaxf(LN2 * flog2(fmaxf(1.0f - pr, 1e-12f)), -100.0f);
                }
            }
            int slot = b * SEG + blockIdx.x * 256 + myslot;
            pbox_c[slot] = make_float4(pcx, pcy, pw, ph);
            rec_c[slot] = make_float4(__uint_as_float(m), sc, suml1p, cf);
            cmp[slot] = a;
        }
    }
    __syncthreads();
    if (tid == 0) cnt[b * K1_GX + blockIdx.x] = lcnt;   // unconditional: no memset needed

    // wave-reduce bce0(conf), one store per wave
    float v = bce0_conf;
    for (int off = 32; off; off >>= 1) v += __shfl_down(v, off, 64);
    if ((tid & 63) == 0) {
        int wave = (blockIdx.y * gridDim.x + blockIdx.x) * 4 + (tid >> 6);
        part[wave] = v;
    }
}

// ---------- kernel 23: per-wave dual top-10 + in-block resolve + loss partials ----------
// One block per batch b, 16 waves = 16 GTs. Wave tournaments need no barriers;
// sel/nsel live in LDS; resolve recomputes per-anchor values from raw inputs
// (bit-identical expressions to k1). No device-scope fences (R8 lesson).
__global__ __launch_bounds__(1024, 4) void k23_assign_resolve(
    const float* __restrict__ gtb, const int* __restrict__ gtc,
    const float4* __restrict__ pbox_c, const float4* __restrict__ rec_c,
    const int* __restrict__ cmp, const int* __restrict__ cnt,
    const float* __restrict__ p8, const float* __restrict__ p16, const float* __restrict__ p32,
    float4* __restrict__ part3) {
    __shared__ unsigned tag[A_TOT];
    __shared__ int cnt_s[K1_GX];
    __shared__ int sel_s[NG * 10];
    __shared__ int nsel_s[NG];
    __shared__ float gb[NG * 4];
    __shared__ int gc[NG];
    __shared__ float red[1024];
    int b = blockIdx.x;
    int tid = threadIdx.x;
    int g = tid >> 6;        // wave id == GT id
    int lane = tid & 63;

    if (tid < K1_GX) cnt_s[tid] = cnt[b * K1_GX + tid];
    if (tid < NG * 4) gb[tid] = gtb[b * NG * 4 + tid];
    if (tid < NG) gc[tid] = gtc[b * NG + tid];
    for (int j = tid; j < A_TOT; j += 1024) tag[j] = 0;
    __syncthreads();

    float gcx = gb[g * 4], gcy = gb[g * 4 + 1];
    float gw = gb[g * 4 + 2], gh = gb[g * 4 + 3];
    int cg = gc[g];

    unsigned long long topI[10];   // masked-iou keys, descending
    unsigned long long topC[10];   // cost keys, ascending
#pragma unroll
    for (int i = 0; i < 10; i++) { topI[i] = 0ull; topC[i] = 0xFFFFFFFFFFFFFFFFull; }

    // wave-local scan over the compacted union list
    for (int j = lane; j < SEG; j += 64) {
        if ((j & 255) >= cnt_s[j >> 8]) continue;
        int slot = b * SEG + j;
        float4 pb = pbox_c[slot];
        float4 rc = rec_c[slot];
        int a = cmp[slot];
        unsigned m = __float_as_uint(rc.x);
        float iou = iou_cxcywh(gcx, gcy, gw, gh, pb.x, pb.y, pb.z, pb.w);

        int hw, HW, W;
        float s;
        const float* base = lvl_base(a, b, p8, p16, p32, hw, HW, W, s);
        float x = base[(5 + cg) * HW + hw];
        float d = dval_of(x, rc.y);
        float cost = -(d + rc.z) - 3.0f * LN2 * flog2(iou + 1e-8f);
        if (!((m >> g) & 1u)) cost += 100000.0f;

        if (iou > 0.0f) {
            unsigned long long kI = ((unsigned long long)__float_as_uint(iou) << 32) | (unsigned)a;
            if (kI > topI[9]) {
                unsigned long long v = kI;
#pragma unroll
                for (int i2 = 0; i2 < 10; i2++) {
                    unsigned long long big = umax64(topI[i2], v);
                    v = umin64(topI[i2], v);
                    topI[i2] = big;
                }
            }
        }
        unsigned long long kC = ((unsigned long long)__float_as_uint(cost) << 32) | (unsigned)a;
        if (kC < topC[9]) {
            unsigned long long v = kC;
#pragma unroll
            for (int i2 = 0; i2 < 10; i2++) {
                unsigned long long sml = umin64(topC[i2], v);
                v = umax64(topC[i2], v);
                topC[i2] = sml;
            }
        }
    }

    // wave tournament 1: sum of top-10 masked iou
    float ksum = 0.0f;
#pragma unroll
    for (int rr = 0; rr < 10; rr++) {
        unsigned long long w = topI[0];
        for (int off = 32; off; off >>= 1) w = umax64(w, __shfl_xor(w, off, 64));
        ksum += __uint_as_float((unsigned)(w >> 32));
        if (topI[0] == w) {
#pragma unroll
            for (int i = 0; i < 9; i++) topI[i] = topI[i + 1];
            topI[9] = 0ull;
        }
    }
    int dynk = (int)ksum;
    if (dynk < 1) dynk = 1;
    if (dynk > 10) dynk = 10;

    // wave tournament 2: 10 smallest costs
#pragma unroll
    for (int rr = 0; rr < 10; rr++) {
        unsigned long long w = topC[0];
        for (int off = 32; off; off >>= 1) w = umin64(w, __shfl_xor(w, off, 64));
        if (lane == 0) sel_s[g * 10 + rr] = (int)(w & 0xffffffffu);
        if (topC[0] == w) {
#pragma unroll
            for (int i = 0; i < 9; i++) topC[i] = topC[i + 1];
            topC[9] = 0xFFFFFFFFFFFFFFFFull;
        }
    }
    if (lane == 0) nsel_s[g] = dynk;
    __syncthreads();

    // claim counting
    if (tid < NG * 10) {
        int g2 = tid / 10, k = tid % 10;
        if (k < nsel_s[g2])
            atomicAdd(&tag[sel_s[g2 * 10 + k]], 0x10000u + (unsigned)(g2 + 1));
    }
    __syncthreads();

    // resolve + loss partials (recompute from raw inputs; expressions match k1)
    float lbox = 0.0f, lconfc = 0.0f, lcls = 0.0f, nfg = 0.0f;
    for (int a = tid; a < A_TOT; a += 1024) {
        unsigned t = tag[a];
        unsigned cnt2 = t >> 16;
        if (!cnt2) continue;
        int hw, HW, W;
        float s;
        const float* base = lvl_base(a, b, p8, p16, p32, hw, HW, W, s);
        float tx = base[hw], ty = base[HW + hw];
        float tw = base[2 * HW + hw], th = base[3 * HW + hw];
        float cf = base[4 * HW + hw];
        int gx = hw % W, gy = hw / W;
        float pcx = (tx + (float)gx) * s;
        float pcy = (ty + (float)gy) * s;
        float pw = fexp2(tw * L2E) * s;
        float ph = fexp2(th * L2E) * s;

        int gs;
        if (cnt2 == 1) {
            gs = (int)(t & 0xffffu) - 1;
        } else {
            // argmin over g; sp term is constant across g and drops out
            float sc = frcp(1.0f + fexp2(-cf * L2E));
            float xc = ((float)gx + 0.5f) * s;
            float yc = ((float)gy + 0.5f) * s;
            float r = 2.5f * s;
            float bc = 3.402823466e38f;
            gs = 0;
            for (int g2 = 0; g2 < NG; g2++) {
                float bx = gb[g2 * 4], by = gb[g2 * 4 + 1];
                float bw = gb[g2 * 4 + 2], bh = gb[g2 * 4 + 3];
                float iou = iou_cxcywh(bx, by, bw, bh, pcx, pcy, pw, ph);
                float x = base[(5 + gc[g2]) * HW + hw];
                float d = dval_of(x, sc);
                float c = -d - 3.0f * LN2 * flog2(iou + 1e-8f);
                bool ib = (xc > bx - bw * 0.5f) && (bx + bw * 0.5f > xc) &&
                          (yc > by - bh * 0.5f) && (by + bh * 0.5f > yc);
                bool im = (xc > bx - r) && (bx + r > xc) &&
                          (yc > by - r) && (by + r > yc);
                if (!(ib && im)) c += 100000.0f;
                if (c < bc) { bc = c; gs = g2; }
            }
        }
        float miou = iou_cxcywh(gb[gs * 4], gb[gs * 4 + 1], gb[gs * 4 + 2], gb[gs * 4 + 3],
                                pcx, pcy, pw, ph);
        int cid = gc[gs];
        float xcid = base[(5 + cid) * HW + hw];

        // on-demand s0 = sum_c bce0(x_c)
        float s0 = 0.0f;
        const float* cbase = base + 5 * HW + hw;
#pragma unroll
        for (int cc = 0; cc < NC; cc += 20) {
            float x[20];
#pragma unroll
            for (int jj = 0; jj < 20; jj++) x[jj] = cbase[(cc + jj) * HW];
#pragma unroll
            for (int jj = 0; jj < 20; jj++) {
                float u = fexp2(-x[jj] * L2E);
                s0 += x[jj] + LN2 * flog2(1.0f + u);
            }
        }

        lbox += 1.0f - miou * miou;
        lconfc -= cf;
        lcls += s0 - xcid * miou;
        nfg += 1.0f;
    }

    // block reduce the four partials -> one float4 per batch
    float vals[4] = {lbox, lconfc, lcls, nfg};
    float outv[4];
    for (int i = 0; i < 4; i++) {
        red[tid] = vals[i];
        __syncthreads();
        for (int s2 = 512; s2 > 0; s2 >>= 1) {
            if (tid < s2) red[tid] += red[tid + s2];
            __syncthreads();
        }
        outv[i] = red[0];
        __syncthreads();
    }
    if (tid == 0) part3[b] = make_float4(outv[0], outv[1], outv[2], outv[3]);
}

// ---------- kernel 4: sum partials + final scalar ----------
__global__ __launch_bounds__(256) void k4_final(
    const float* __restrict__ part, const float4* __restrict__ part3, float* __restrict__ out) {
    __shared__ float red[256];
    int tid = threadIdx.x;
    float v = 0.0f;
    for (int i = tid; i < NWAVE; i += 256) v += part[i];
    float4 p = (tid < NB) ? part3[tid] : make_float4(0.f, 0.f, 0.f, 0.f);
    float vals[5] = {v, p.x, p.y, p.z, p.w};
    float tot[5];
    for (int i = 0; i < 5; i++) {
        red[tid] = vals[i];
        __syncthreads();
        for (int s2 = 128; s2 > 0; s2 >>= 1) {
            if (tid < s2) red[tid] += red[tid + s2];
            __syncthreads();
        }
        tot[i] = red[0];
        __syncthreads();
    }
    if (tid == 0) {
        float nfg = tot[4];
        if (nfg < 1.0f) nfg = 1.0f;
        out[0] = (5.0f * tot[1] + (tot[0] + tot[2]) + tot[3]) / nfg;
    }
}

// ---------- launch ----------
extern "C" void kernel_launch(void* const* d_in, const int* in_sizes, int n_in,
                              void* d_out, int out_size, void* d_ws, size_t ws_size,
                              hipStream_t stream) {
    const float* p8  = (const float*)d_in[0];
    const float* p16 = (const float*)d_in[1];
    const float* p32 = (const float*)d_in[2];
    const float* gtb = (const float*)d_in[3];
    const int*   gtc = (const int*)d_in[4];

    char* w = (char*)d_ws;
    float4* pbox_c = (float4*)w;               w += (size_t)NB * SEG * sizeof(float4);
    float4* rec_c  = (float4*)w;               w += (size_t)NB * SEG * sizeof(float4);
    int* cmp       = (int*)w;                  w += (size_t)NB * SEG * sizeof(int);
    int* cnt       = (int*)w;                  w += (size_t)NB * K1_GX * sizeof(int);
    float* part    = (float*)w;                w += (size_t)NWAVE * sizeof(float);
    float4* part3  = (float4*)w;               w += (size_t)NB * sizeof(float4);

    k1_decode<<<dim3(K1_GX, NB), 256, 0, stream>>>(
        p8, p16, p32, gtb, pbox_c, rec_c, cmp, cnt, part);
    k23_assign_resolve<<<NB, 1024, 0, stream>>>(gtb, gtc, pbox_c, rec_c, cmp, cnt,
                                                p8, p16, p32, part3);
    k4_final<<<1, 256, 0, stream>>>(part, part3, (float*)d_out);
}

// Round 11
// 190.381 us; speedup vs baseline: 1.2383x; 1.2383x over previous
//
#include <hip/hip_runtime.h>
#include <hip/hip_bf16.h>

#define A_TOT 8400
#define NB 32
#define NG 16
#define NC 80

#define K1_GX 33                  // ceil(8400/256)
#define SEG   (K1_GX * 256)       // 8448 compaction slots per batch
#define NWAVE (K1_GX * NB * 4)    // per-wave conf partials
#define K3_CH 8                   // anchor chunks per batch
#define K3_W  1050                // anchors per chunk (8*1050 = 8400)
#define K3_BLOCKS (K3_CH * NB)

#define L2E 1.44269504088896340736f
#define LN2 0.69314718055994530942f

// ---------- fast native transcendentals ----------
__device__ inline float fexp2(float x) { return __builtin_amdgcn_exp2f(x); }
__device__ inline float flog2(float x) { return __builtin_amdgcn_logf(x); }
__device__ inline float frcp(float x)  { return __builtin_amdgcn_rcpf(x); }
__device__ inline float fsqrtf_(float x) { return __builtin_amdgcn_sqrtf(x); }

__device__ inline float iou_cxcywh(float acx, float acy, float aw, float ah,
                                   float bcx, float bcy, float bw, float bh) {
    float tlx = fmaxf(acx - aw * 0.5f, bcx - bw * 0.5f);
    float tly = fmaxf(acy - ah * 0.5f, bcy - bh * 0.5f);
    float brx = fminf(acx + aw * 0.5f, bcx + bw * 0.5f);
    float bry = fminf(acy + ah * 0.5f, bcy + bh * 0.5f);
    float w = fmaxf(brx - tlx, 0.0f);
    float h = fmaxf(bry - tly, 0.0f);
    float inter = w * h;
    return inter / (aw * ah + bw * bh - inter + 1e-16f);
}

// d = logp - log1mp for class logit x and conf-sigmoid sc
__device__ inline float dval_of(float x, float sc) {
    float u = fexp2(-x * L2E);
    float sx = frcp(1.0f + u);
    float pr = fsqrtf_(sx * sc);
    float lp  = fmaxf(LN2 * flog2(fmaxf(pr, 1e-12f)), -100.0f);
    float l1p = fmaxf(LN2 * flog2(fmaxf(1.0f - pr, 1e-12f)), -100.0f);
    return lp - l1p;
}

__device__ inline unsigned long long umax64(unsigned long long a, unsigned long long b) {
    return a > b ? a : b;
}
__device__ inline unsigned long long umin64(unsigned long long a, unsigned long long b) {
    return a < b ? a : b;
}

// resolve anchor index -> level base / hw / HW / W / stride
__device__ inline const float* lvl_base(int a, int b, const float* p8, const float* p16,
                                        const float* p32, int& hw, int& HW, int& W, float& s) {
    if (a < 6400) { hw = a;        HW = 6400; W = 80; s = 8.0f;  return p8  + (size_t)b * 85 * 6400; }
    if (a < 8000) { hw = a - 6400; HW = 1600; W = 40; s = 16.0f; return p16 + (size_t)b * 85 * 1600; }
    { hw = a - 8000; HW = 400; W = 20; s = 32.0f; return p32 + (size_t)b * 85 * 400; }
}

// ---------- kernel 1: decode + masks; per-block-segment union compaction ----------
// pbox_c/rec_c/cmp are SLOT-indexed (slot = b*SEG + bx*256 + local), union only.
// rec_c = {umask bits, sigmoid(conf), sum log1mp, conf logit}. cnt[b*33+bx] = count
// (written unconditionally -> no memset dispatch needed).
__global__ __launch_bounds__(256) void k1_decode(
    const float* __restrict__ p8, const float* __restrict__ p16, const float* __restrict__ p32,
    const float* __restrict__ gtb,
    float4* __restrict__ pbox_c, float4* __restrict__ rec_c,
    int* __restrict__ cmp, int* __restrict__ cnt, float* __restrict__ part) {
    __shared__ int lcnt;
    int b = blockIdx.y;
    int tid = threadIdx.x;
    int a = blockIdx.x * 256 + tid;
    if (tid == 0) lcnt = 0;
    __syncthreads();

    float bce0_conf = 0.0f;
    if (a < A_TOT) {
        int hw, HW, W;
        float s;
        const float* base = lvl_base(a, b, p8, p16, p32, hw, HW, W, s);

        float cf = base[4 * HW + hw];
        float uc = fexp2(-cf * L2E);
        float suc = 1.0f + uc;
        float sc = frcp(suc);
        bce0_conf = cf + LN2 * flog2(suc);    // bce0(conf)

        int gx = hw % W, gy = hw / W;
        float xc = ((float)gx + 0.5f) * s;
        float yc = ((float)gy + 0.5f) * s;
        unsigned m = 0;
        bool uni = false;
        float r = 2.5f * s;
#pragma unroll 4
        for (int g = 0; g < NG; g++) {
            float gcx = gtb[(b * NG + g) * 4 + 0];
            float gcy = gtb[(b * NG + g) * 4 + 1];
            float gw  = gtb[(b * NG + g) * 4 + 2];
            float gh  = gtb[(b * NG + g) * 4 + 3];
            bool ib = (xc > gcx - gw * 0.5f) && (gcx + gw * 0.5f > xc) &&
                      (yc > gcy - gh * 0.5f) && (gcy + gh * 0.5f > yc);
            bool im = (xc > gcx - r) && (gcx + r > xc) &&
                      (yc > gcy - r) && (gcy + r > yc);
            uni |= (ib || im);
            if (ib && im) m |= (1u << g);
        }
        if (uni) {
            m |= (1u << 16);
            int myslot = atomicAdd(&lcnt, 1);
            // box decode (union only)
            float tx = base[hw], ty = base[HW + hw];
            float tw = base[2 * HW + hw], th = base[3 * HW + hw];
            float pcx = (tx + (float)gx) * s;
            float pcy = (ty + (float)gy) * s;
            float pw = fexp2(tw * L2E) * s;
            float ph = fexp2(th * L2E) * s;
            // class-sum (union only); predicated but lanes stay clustered
            float suml1p = 0.0f;
            const float* cbase = base + 5 * HW + hw;
#pragma unroll
            for (int cc = 0; cc < NC; cc += 20) {
                float x[20];
#pragma unroll
                for (int j = 0; j < 20; j++) x[j] = cbase[(cc + j) * HW];
#pragma unroll
                for (int j = 0; j < 20; j++) {
                    float u = fexp2(-x[j] * L2E);
                    float pr = fsqrtf_(frcp(1.0f + u) * sc);
                    suml1p += fmaxf(LN2 * flog2(fmaxf(1.0f - pr, 1e-12f)), -100.0f);
                }
            }
            int slot = b * SEG + blockIdx.x * 256 + myslot;
            pbox_c[slot] = make_float4(pcx, pcy, pw, ph);
            rec_c[slot] = make_float4(__uint_as_float(m), sc, suml1p, cf);
            cmp[slot] = a;
        }
    }
    __syncthreads();
    if (tid == 0) cnt[b * K1_GX + blockIdx.x] = lcnt;

    // wave-reduce bce0(conf), one store per wave
    float v = bce0_conf;
    for (int off = 32; off; off >>= 1) v += __shfl_down(v, off, 64);
    if ((tid & 63) == 0) {
        int wave = (blockIdx.y * gridDim.x + blockIdx.x) * 4 + (tid >> 6);
        part[wave] = v;
    }
}

// ---------- kernel 2: per-(b,g) dual top-10 over the compacted segment list ----------
// 512 blocks x 256 threads (R9 parallelism). Per-thread items <=33 (one per
// segment) -> 10-deep register lists are lossless. Keys embed the original
// anchor index so ordering/tie-break matches the reference exactly.
__global__ __launch_bounds__(256, 4) void k2_assign(
    const float* __restrict__ gtb, const int* __restrict__ gtc,
    const float4* __restrict__ pbox_c, const float4* __restrict__ rec_c,
    const int* __restrict__ cmp, const int* __restrict__ cnt,
    const float* __restrict__ p8, const float* __restrict__ p16, const float* __restrict__ p32,
    int* __restrict__ sel, int* __restrict__ nsel) {
    __shared__ unsigned long long wred[4];
    __shared__ int cnt_s[K1_GX];
    int blk = blockIdx.x;            // b*16+g
    int b = blk >> 4, g = blk & 15;
    int tid = threadIdx.x;

    if (tid < K1_GX) cnt_s[tid] = cnt[b * K1_GX + tid];
    __syncthreads();

    float gcx = gtb[blk * 4 + 0], gcy = gtb[blk * 4 + 1];
    float gw = gtb[blk * 4 + 2],  gh = gtb[blk * 4 + 3];
    int cg = gtc[blk];               // block-uniform class id

    unsigned long long topI[10];   // masked-iou keys, descending
    unsigned long long topC[10];   // cost keys, ascending
#pragma unroll
    for (int i = 0; i < 10; i++) { topI[i] = 0ull; topC[i] = 0xFFFFFFFFFFFFFFFFull; }

    for (int j = tid; j < SEG; j += 256) {
        if (tid >= cnt_s[j >> 8]) continue;      // j&255 == tid
        int slot = b * SEG + j;
        float4 pb = pbox_c[slot];
        float4 rc = rec_c[slot];
        int a = cmp[slot];
        unsigned m = __float_as_uint(rc.x);
        float iou = iou_cxcywh(gcx, gcy, gw, gh, pb.x, pb.y, pb.z, pb.w);

        int hw, HW, W;
        float s;
        const float* base = lvl_base(a, b, p8, p16, p32, hw, HW, W, s);
        float x = base[(5 + cg) * HW + hw];
        float d = dval_of(x, rc.y);
        float cost = -(d + rc.z) - 3.0f * LN2 * flog2(iou + 1e-8f);
        if (!((m >> g) & 1u)) cost += 100000.0f;

        if (iou > 0.0f) {
            unsigned long long kI = ((unsigned long long)__float_as_uint(iou) << 32) | (unsigned)a;
            if (kI > topI[9]) {
                unsigned long long v = kI;
#pragma unroll
                for (int i2 = 0; i2 < 10; i2++) {
                    unsigned long long big = umax64(topI[i2], v);
                    v = umin64(topI[i2], v);
                    topI[i2] = big;
                }
            }
        }
        unsigned long long kC = ((unsigned long long)__float_as_uint(cost) << 32) | (unsigned)a;
        if (kC < topC[9]) {
            unsigned long long v = kC;
#pragma unroll
            for (int i2 = 0; i2 < 10; i2++) {
                unsigned long long sml = umin64(topC[i2], v);
                v = umax64(topC[i2], v);
                topC[i2] = sml;
            }
        }
    }

    // ---- tournament 1: sum of global top-10 masked iou (descending) ----
    float ksum = 0.0f;
    for (int rr = 0; rr < 10; rr++) {
        unsigned long long h = topI[0];
        for (int off = 32; off; off >>= 1) h = umax64(h, __shfl_xor(h, off, 64));
        if ((tid & 63) == 0) wred[tid >> 6] = h;
        __syncthreads();
        unsigned long long w = umax64(umax64(wred[0], wred[1]), umax64(wred[2], wred[3]));
        ksum += __uint_as_float((unsigned)(w >> 32));
        if (topI[0] == w) {
#pragma unroll
            for (int i = 0; i < 9; i++) topI[i] = topI[i + 1];
            topI[9] = 0ull;
        }
        __syncthreads();
    }
    int dynk = (int)ksum;            // truncation matches astype(int32)
    if (dynk < 1) dynk = 1;
    if (dynk > 10) dynk = 10;

    // ---- tournament 2: 10 smallest costs (ascending, lowest-index ties) ----
    for (int rr = 0; rr < 10; rr++) {
        unsigned long long h = topC[0];
        for (int off = 32; off; off >>= 1) h = umin64(h, __shfl_xor(h, off, 64));
        if ((tid & 63) == 0) wred[tid >> 6] = h;
        __syncthreads();
        unsigned long long w = umin64(umin64(wred[0], wred[1]), umin64(wred[2], wred[3]));
        if (tid == 0) sel[blk * 10 + rr] = (int)(w & 0xffffffffu);
        if (topC[0] == w) {
#pragma unroll
            for (int i = 0; i < 9; i++) topC[i] = topC[i + 1];
            topC[9] = 0xFFFFFFFFFFFFFFFFull;
        }
        __syncthreads();
    }
    if (tid == 0) nsel[blk] = dynk;
}

// ---------- kernel 3: conflict resolution + loss partials (recompute from raw) ----------
__global__ __launch_bounds__(256) void k3_resolve(
    const float* __restrict__ gtb, const int* __restrict__ gtc,
    const int* __restrict__ sel, const int* __restrict__ nsel,
    const float* __restrict__ p8, const float* __restrict__ p16, const float* __restrict__ p32,
    float4* __restrict__ part3) {
    __shared__ unsigned tag[K3_W];
    __shared__ float gb[NG * 4];
    __shared__ int gc[NG];
    __shared__ float red[256];
    int b = blockIdx.y, chunk = blockIdx.x, tid = threadIdx.x;
    int a0 = chunk * K3_W;

    for (int j = tid; j < K3_W; j += 256) tag[j] = 0;
    if (tid < NG * 4) gb[tid] = gtb[b * NG * 4 + tid];
    if (tid < NG) gc[tid] = gtc[b * NG + tid];
    __syncthreads();

    if (tid < NG * 10) {
        int g = tid / 10, k = tid % 10;
        if (k < nsel[b * NG + g]) {
            int a = sel[(b * NG + g) * 10 + k];
            if (a >= a0 && a < a0 + K3_W)
                atomicAdd(&tag[a - a0], 0x10000u + (unsigned)(g + 1));
        }
    }
    __syncthreads();

    float lbox = 0.0f, lconfc = 0.0f, lcls = 0.0f, nfg = 0.0f;
    for (int j = tid; j < K3_W; j += 256) {
        unsigned t = tag[j];
        unsigned cnt2 = t >> 16;
        if (!cnt2) continue;
        int a = a0 + j;
        int hw, HW, W;
        float s;
        const float* base = lvl_base(a, b, p8, p16, p32, hw, HW, W, s);
        float tx = base[hw], ty = base[HW + hw];
        float tw = base[2 * HW + hw], th = base[3 * HW + hw];
        float cf = base[4 * HW + hw];
        int gx = hw % W, gy = hw / W;
        float pcx = (tx + (float)gx) * s;
        float pcy = (ty + (float)gy) * s;
        float pw = fexp2(tw * L2E) * s;
        float ph = fexp2(th * L2E) * s;

        int gs;
        if (cnt2 == 1) {
            gs = (int)(t & 0xffffu) - 1;
        } else {
            // argmin over g; sp term is constant across g and drops out.
            // Tagged anchors are union anchors -> no 1e15 branch needed.
            float sc = frcp(1.0f + fexp2(-cf * L2E));
            float xc = ((float)gx + 0.5f) * s;
            float yc = ((float)gy + 0.5f) * s;
            float r = 2.5f * s;
            float bc = 3.402823466e38f;
            gs = 0;
            for (int g2 = 0; g2 < NG; g2++) {
                float bx = gb[g2 * 4], by = gb[g2 * 4 + 1];
                float bw = gb[g2 * 4 + 2], bh = gb[g2 * 4 + 3];
                float iou = iou_cxcywh(bx, by, bw, bh, pcx, pcy, pw, ph);
                float x = base[(5 + gc[g2]) * HW + hw];
                float d = dval_of(x, sc);
                float c = -d - 3.0f * LN2 * flog2(iou + 1e-8f);
                bool ib = (xc > bx - bw * 0.5f) && (bx + bw * 0.5f > xc) &&
                          (yc > by - bh * 0.5f) && (by + bh * 0.5f > yc);
                bool im = (xc > bx - r) && (bx + r > xc) &&
                          (yc > by - r) && (by + r > yc);
                if (!(ib && im)) c += 100000.0f;
                if (c < bc) { bc = c; gs = g2; }
            }
        }
        float miou = iou_cxcywh(gb[gs * 4], gb[gs * 4 + 1], gb[gs * 4 + 2], gb[gs * 4 + 3],
                                pcx, pcy, pw, ph);
        int cid = gc[gs];
        float xcid = base[(5 + cid) * HW + hw];

        // on-demand s0 = sum_c bce0(x_c)
        float s0 = 0.0f;
        const float* cbase = base + 5 * HW + hw;
#pragma unroll
        for (int cc = 0; cc < NC; cc += 20) {
            float x[20];
#pragma unroll
            for (int jj = 0; jj < 20; jj++) x[jj] = cbase[(cc + jj) * HW];
#pragma unroll
            for (int jj = 0; jj < 20; jj++) {
                float u = fexp2(-x[jj] * L2E);
                s0 += x[jj] + LN2 * flog2(1.0f + u);
            }
        }

        lbox += 1.0f - miou * miou;
        lconfc -= cf;
        lcls += s0 - xcid * miou;
        nfg += 1.0f;
    }

    // block reduce the four partials -> one float4 store (no atomics)
    float vals[4] = {lbox, lconfc, lcls, nfg};
    float outv[4];
    for (int i = 0; i < 4; i++) {
        red[tid] = vals[i];
        __syncthreads();
        for (int s2 = 128; s2 > 0; s2 >>= 1) {
            if (tid < s2) red[tid] += red[tid + s2];
            __syncthreads();
        }
        outv[i] = red[0];
        __syncthreads();
    }
    if (tid == 0)
        part3[b * K3_CH + chunk] = make_float4(outv[0], outv[1], outv[2], outv[3]);
}

// ---------- kernel 4: sum partials + final scalar ----------
__global__ __launch_bounds__(256) void k4_final(
    const float* __restrict__ part, const float4* __restrict__ part3, float* __restrict__ out) {
    __shared__ float red[256];
    int tid = threadIdx.x;
    float v = 0.0f;
    for (int i = tid; i < NWAVE; i += 256) v += part[i];
    float4 p = part3[tid];               // exactly K3_BLOCKS = 256 entries
    float vals[5] = {v, p.x, p.y, p.z, p.w};
    float tot[5];
    for (int i = 0; i < 5; i++) {
        red[tid] = vals[i];
        __syncthreads();
        for (int s2 = 128; s2 > 0; s2 >>= 1) {
            if (tid < s2) red[tid] += red[tid + s2];
            __syncthreads();
        }
        tot[i] = red[0];
        __syncthreads();
    }
    if (tid == 0) {
        float nfg = tot[4];
        if (nfg < 1.0f) nfg = 1.0f;
        out[0] = (5.0f * tot[1] + (tot[0] + tot[2]) + tot[3]) / nfg;
    }
}

// ---------- launch ----------
extern "C" void kernel_launch(void* const* d_in, const int* in_sizes, int n_in,
                              void* d_out, int out_size, void* d_ws, size_t ws_size,
                              hipStream_t stream) {
    const float* p8  = (const float*)d_in[0];
    const float* p16 = (const float*)d_in[1];
    const float* p32 = (const float*)d_in[2];
    const float* gtb = (const float*)d_in[3];
    const int*   gtc = (const int*)d_in[4];

    char* w = (char*)d_ws;
    float4* pbox_c = (float4*)w;               w += (size_t)NB * SEG * sizeof(float4);
    float4* rec_c  = (float4*)w;               w += (size_t)NB * SEG * sizeof(float4);
    int* cmp       = (int*)w;                  w += (size_t)NB * SEG * sizeof(int);
    int* cnt       = (int*)w;                  w += (size_t)NB * K1_GX * sizeof(int);
    int* sel       = (int*)w;                  w += (size_t)NB * NG * 10 * sizeof(int);
    int* nsel      = (int*)w;                  w += (size_t)NB * NG * sizeof(int);
    float* part    = (float*)w;                w += (size_t)NWAVE * sizeof(float);
    float4* part3  = (float4*)w;               w += (size_t)K3_BLOCKS * sizeof(float4);

    k1_decode<<<dim3(K1_GX, NB), 256, 0, stream>>>(
        p8, p16, p32, gtb, pbox_c, rec_c, cmp, cnt, part);
    k2_assign<<<NB * NG, 256, 0, stream>>>(gtb, gtc, pbox_c, rec_c, cmp, cnt,
                                           p8, p16, p32, sel, nsel);
    k3_resolve<<<dim3(K3_CH, NB), 256, 0, stream>>>(gtb, gtc, sel, nsel,
                                                    p8, p16, p32, part3);
    k4_final<<<1, 256, 0, stream>>>(part, part3, (float*)d_out);
}

// Round 12
// 173.195 us; speedup vs baseline: 1.3612x; 1.0992x over previous
//
#include <hip/hip_runtime.h>
#include <hip/hip_bf16.h>

#define A_TOT 8400
#define NB 32
#define NG 16
#define NC 80

#define K1_GX 33                  // ceil(8400/256)
#define SEG   (K1_GX * 256)       // 8448 compaction slots per batch
#define NWAVE (K1_GX * NB * 4)    // per-wave conf partials
#define K3_CH 8                   // anchor chunks per batch
#define K3_W  1050                // anchors per chunk (8*1050 = 8400)
#define K3_BLOCKS (K3_CH * NB)

#define L2E 1.44269504088896340736f
#define LN2 0.69314718055994530942f

// ---------- fast native transcendentals ----------
__device__ inline float fexp2(float x) { return __builtin_amdgcn_exp2f(x); }
__device__ inline float flog2(float x) { return __builtin_amdgcn_logf(x); }
__device__ inline float frcp(float x)  { return __builtin_amdgcn_rcpf(x); }
__device__ inline float fsqrtf_(float x) { return __builtin_amdgcn_sqrtf(x); }

__device__ inline float iou_cxcywh(float acx, float acy, float aw, float ah,
                                   float bcx, float bcy, float bw, float bh) {
    float tlx = fmaxf(acx - aw * 0.5f, bcx - bw * 0.5f);
    float tly = fmaxf(acy - ah * 0.5f, bcy - bh * 0.5f);
    float brx = fminf(acx + aw * 0.5f, bcx + bw * 0.5f);
    float bry = fminf(acy + ah * 0.5f, bcy + bh * 0.5f);
    float w = fmaxf(brx - tlx, 0.0f);
    float h = fmaxf(bry - tly, 0.0f);
    float inter = w * h;
    return inter / (aw * ah + bw * bh - inter + 1e-16f);
}

// d = logp - log1mp for class logit x and conf-sigmoid sc
__device__ inline float dval_of(float x, float sc) {
    float u = fexp2(-x * L2E);
    float sx = frcp(1.0f + u);
    float pr = fsqrtf_(sx * sc);
    float lp  = fmaxf(LN2 * flog2(fmaxf(pr, 1e-12f)), -100.0f);
    float l1p = fmaxf(LN2 * flog2(fmaxf(1.0f - pr, 1e-12f)), -100.0f);
    return lp - l1p;
}

__device__ inline unsigned long long umax64(unsigned long long a, unsigned long long b) {
    return a > b ? a : b;
}
__device__ inline unsigned long long umin64(unsigned long long a, unsigned long long b) {
    return a < b ? a : b;
}

// resolve anchor index -> level base / hw / HW / W / stride
__device__ inline const float* lvl_base(int a, int b, const float* p8, const float* p16,
                                        const float* p32, int& hw, int& HW, int& W, float& s) {
    if (a < 6400) { hw = a;        HW = 6400; W = 80; s = 8.0f;  return p8  + (size_t)b * 85 * 6400; }
    if (a < 8000) { hw = a - 6400; HW = 1600; W = 40; s = 16.0f; return p16 + (size_t)b * 85 * 1600; }
    { hw = a - 8000; HW = 400; W = 20; s = 32.0f; return p32 + (size_t)b * 85 * 400; }
}

// ---------- kernel 1: decode + masks; per-block-segment union compaction ----------
// pbox_c/rec_c/cmp are SLOT-indexed (slot = b*SEG + bx*256 + local), union only.
// rec_c = {umask bits, sigmoid(conf), sum log1mp, conf logit}. cnt[b*33+bx] = count
// (written unconditionally -> no memset dispatch needed).
__global__ __launch_bounds__(256) void k1_decode(
    const float* __restrict__ p8, const float* __restrict__ p16, const float* __restrict__ p32,
    const float* __restrict__ gtb,
    float4* __restrict__ pbox_c, float4* __restrict__ rec_c,
    int* __restrict__ cmp, int* __restrict__ cnt, float* __restrict__ part) {
    __shared__ int lcnt;
    int b = blockIdx.y;
    int tid = threadIdx.x;
    int a = blockIdx.x * 256 + tid;
    if (tid == 0) lcnt = 0;
    __syncthreads();

    float bce0_conf = 0.0f;
    if (a < A_TOT) {
        int hw, HW, W;
        float s;
        const float* base = lvl_base(a, b, p8, p16, p32, hw, HW, W, s);

        float cf = base[4 * HW + hw];
        float uc = fexp2(-cf * L2E);
        float suc = 1.0f + uc;
        float sc = frcp(suc);
        bce0_conf = cf + LN2 * flog2(suc);    // bce0(conf)

        int gx = hw % W, gy = hw / W;
        float xc = ((float)gx + 0.5f) * s;
        float yc = ((float)gy + 0.5f) * s;
        unsigned m = 0;
        bool uni = false;
        float r = 2.5f * s;
#pragma unroll 4
        for (int g = 0; g < NG; g++) {
            float gcx = gtb[(b * NG + g) * 4 + 0];
            float gcy = gtb[(b * NG + g) * 4 + 1];
            float gw  = gtb[(b * NG + g) * 4 + 2];
            float gh  = gtb[(b * NG + g) * 4 + 3];
            bool ib = (xc > gcx - gw * 0.5f) && (gcx + gw * 0.5f > xc) &&
                      (yc > gcy - gh * 0.5f) && (gcy + gh * 0.5f > yc);
            bool im = (xc > gcx - r) && (gcx + r > xc) &&
                      (yc > gcy - r) && (gcy + r > yc);
            uni |= (ib || im);
            if (ib && im) m |= (1u << g);
        }
        if (uni) {
            m |= (1u << 16);
            int myslot = atomicAdd(&lcnt, 1);
            // box decode (union only)
            float tx = base[hw], ty = base[HW + hw];
            float tw = base[2 * HW + hw], th = base[3 * HW + hw];
            float pcx = (tx + (float)gx) * s;
            float pcy = (ty + (float)gy) * s;
            float pw = fexp2(tw * L2E) * s;
            float ph = fexp2(th * L2E) * s;
            // class-sum (union only); predicated but lanes stay clustered
            float suml1p = 0.0f;
            const float* cbase = base + 5 * HW + hw;
#pragma unroll
            for (int cc = 0; cc < NC; cc += 20) {
                float x[20];
#pragma unroll
                for (int j = 0; j < 20; j++) x[j] = cbase[(cc + j) * HW];
#pragma unroll
                for (int j = 0; j < 20; j++) {
                    float u = fexp2(-x[j] * L2E);
                    float pr = fsqrtf_(frcp(1.0f + u) * sc);
                    suml1p += fmaxf(LN2 * flog2(fmaxf(1.0f - pr, 1e-12f)), -100.0f);
                }
            }
            int slot = b * SEG + blockIdx.x * 256 + myslot;
            pbox_c[slot] = make_float4(pcx, pcy, pw, ph);
            rec_c[slot] = make_float4(__uint_as_float(m), sc, suml1p, cf);
            cmp[slot] = a;
        }
    }
    __syncthreads();
    if (tid == 0) cnt[b * K1_GX + blockIdx.x] = lcnt;

    // wave-reduce bce0(conf), one store per wave
    float v = bce0_conf;
    for (int off = 32; off; off >>= 1) v += __shfl_down(v, off, 64);
    if ((tid & 63) == 0) {
        int wave = (blockIdx.y * gridDim.x + blockIdx.x) * 4 + (tid >> 6);
        part[wave] = v;
    }
}

// ---------- kernel 2: per-(b,g) dual top-10; LDS-densified segment list ----------
// R11's sparse segment scan left 3/4 of threads idle (only tid < cnt_s[seg]
// passed the guard). Densify the slot list into LDS first: all 256 threads
// then scan ~total/256 items each. Keys embed the anchor index -> exact.
__global__ __launch_bounds__(256, 4) void k2_assign(
    const float* __restrict__ gtb, const int* __restrict__ gtc,
    const float4* __restrict__ pbox_c, const float4* __restrict__ rec_c,
    const int* __restrict__ cmp, const int* __restrict__ cnt,
    const float* __restrict__ p8, const float* __restrict__ p16, const float* __restrict__ p32,
    int* __restrict__ sel, int* __restrict__ nsel) {
    __shared__ unsigned long long wred[4];
    __shared__ int cnt_s[K1_GX];
    __shared__ int pfx[K1_GX + 1];
    __shared__ int dense[SEG];           // slot offsets within this batch's SEG
    int blk = blockIdx.x;            // b*16+g
    int b = blk >> 4, g = blk & 15;
    int tid = threadIdx.x;

    if (tid < K1_GX) cnt_s[tid] = cnt[b * K1_GX + tid];
    __syncthreads();
    if (tid == 0) {
        int acc = 0;
        for (int i = 0; i < K1_GX; i++) { pfx[i] = acc; acc += cnt_s[i]; }
        pfx[K1_GX] = acc;
    }
    __syncthreads();
    int total = pfx[K1_GX];
    // expand: dense[pfx[seg]+i] = seg*256+i   (coalesced LDS writes)
    for (int seg = 0; seg < K1_GX; seg++) {
        int c = cnt_s[seg], p0 = pfx[seg];
        for (int i = tid; i < c; i += 256) dense[p0 + i] = seg * 256 + i;
    }
    __syncthreads();

    float gcx = gtb[blk * 4 + 0], gcy = gtb[blk * 4 + 1];
    float gw = gtb[blk * 4 + 2],  gh = gtb[blk * 4 + 3];
    int cg = gtc[blk];               // block-uniform class id

    unsigned long long topI[10];   // masked-iou keys, descending
    unsigned long long topC[10];   // cost keys, ascending
#pragma unroll
    for (int i = 0; i < 10; i++) { topI[i] = 0ull; topC[i] = 0xFFFFFFFFFFFFFFFFull; }

    for (int j = tid; j < total; j += 256) {
        int slot = b * SEG + dense[j];
        float4 pb = pbox_c[slot];
        float4 rc = rec_c[slot];
        int a = cmp[slot];
        unsigned m = __float_as_uint(rc.x);
        float iou = iou_cxcywh(gcx, gcy, gw, gh, pb.x, pb.y, pb.z, pb.w);

        int hw, HW, W;
        float s;
        const float* base = lvl_base(a, b, p8, p16, p32, hw, HW, W, s);
        float x = base[(5 + cg) * HW + hw];
        float d = dval_of(x, rc.y);
        float cost = -(d + rc.z) - 3.0f * LN2 * flog2(iou + 1e-8f);
        if (!((m >> g) & 1u)) cost += 100000.0f;

        if (iou > 0.0f) {
            unsigned long long kI = ((unsigned long long)__float_as_uint(iou) << 32) | (unsigned)a;
            if (kI > topI[9]) {
                unsigned long long v = kI;
#pragma unroll
                for (int i2 = 0; i2 < 10; i2++) {
                    unsigned long long big = umax64(topI[i2], v);
                    v = umin64(topI[i2], v);
                    topI[i2] = big;
                }
            }
        }
        unsigned long long kC = ((unsigned long long)__float_as_uint(cost) << 32) | (unsigned)a;
        if (kC < topC[9]) {
            unsigned long long v = kC;
#pragma unroll
            for (int i2 = 0; i2 < 10; i2++) {
                unsigned long long sml = umin64(topC[i2], v);
                v = umax64(topC[i2], v);
                topC[i2] = sml;
            }
        }
    }

    // ---- tournament 1: sum of global top-10 masked iou (descending) ----
    float ksum = 0.0f;
    for (int rr = 0; rr < 10; rr++) {
        unsigned long long h = topI[0];
        for (int off = 32; off; off >>= 1) h = umax64(h, __shfl_xor(h, off, 64));
        if ((tid & 63) == 0) wred[tid >> 6] = h;
        __syncthreads();
        unsigned long long w = umax64(umax64(wred[0], wred[1]), umax64(wred[2], wred[3]));
        ksum += __uint_as_float((unsigned)(w >> 32));
        if (topI[0] == w) {
#pragma unroll
            for (int i = 0; i < 9; i++) topI[i] = topI[i + 1];
            topI[9] = 0ull;
        }
        __syncthreads();
    }
    int dynk = (int)ksum;            // truncation matches astype(int32)
    if (dynk < 1) dynk = 1;
    if (dynk > 10) dynk = 10;

    // ---- tournament 2: 10 smallest costs (ascending, lowest-index ties) ----
    for (int rr = 0; rr < 10; rr++) {
        unsigned long long h = topC[0];
        for (int off = 32; off; off >>= 1) h = umin64(h, __shfl_xor(h, off, 64));
        if ((tid & 63) == 0) wred[tid >> 6] = h;
        __syncthreads();
        unsigned long long w = umin64(umin64(wred[0], wred[1]), umin64(wred[2], wred[3]));
        if (tid == 0) sel[blk * 10 + rr] = (int)(w & 0xffffffffu);
        if (topC[0] == w) {
#pragma unroll
            for (int i = 0; i < 9; i++) topC[i] = topC[i + 1];
            topC[9] = 0xFFFFFFFFFFFFFFFFull;
        }
        __syncthreads();
    }
    if (tid == 0) nsel[blk] = dynk;
}

// ---------- kernel 3: conflict resolution + loss partials (recompute from raw) ----------
__global__ __launch_bounds__(256) void k3_resolve(
    const float* __restrict__ gtb, const int* __restrict__ gtc,
    const int* __restrict__ sel, const int* __restrict__ nsel,
    const float* __restrict__ p8, const float* __restrict__ p16, const float* __restrict__ p32,
    float4* __restrict__ part3) {
    __shared__ unsigned tag[K3_W];
    __shared__ float gb[NG * 4];
    __shared__ int gc[NG];
    __shared__ float red[256];
    int b = blockIdx.y, chunk = blockIdx.x, tid = threadIdx.x;
    int a0 = chunk * K3_W;

    for (int j = tid; j < K3_W; j += 256) tag[j] = 0;
    if (tid < NG * 4) gb[tid] = gtb[b * NG * 4 + tid];
    if (tid < NG) gc[tid] = gtc[b * NG + tid];
    __syncthreads();

    if (tid < NG * 10) {
        int g = tid / 10, k = tid % 10;
        if (k < nsel[b * NG + g]) {
            int a = sel[(b * NG + g) * 10 + k];
            if (a >= a0 && a < a0 + K3_W)
                atomicAdd(&tag[a - a0], 0x10000u + (unsigned)(g + 1));
        }
    }
    __syncthreads();

    float lbox = 0.0f, lconfc = 0.0f, lcls = 0.0f, nfg = 0.0f;
    for (int j = tid; j < K3_W; j += 256) {
        unsigned t = tag[j];
        unsigned cnt2 = t >> 16;
        if (!cnt2) continue;
        int a = a0 + j;
        int hw, HW, W;
        float s;
        const float* base = lvl_base(a, b, p8, p16, p32, hw, HW, W, s);
        float tx = base[hw], ty = base[HW + hw];
        float tw = base[2 * HW + hw], th = base[3 * HW + hw];
        float cf = base[4 * HW + hw];
        int gx = hw % W, gy = hw / W;
        float pcx = (tx + (float)gx) * s;
        float pcy = (ty + (float)gy) * s;
        float pw = fexp2(tw * L2E) * s;
        float ph = fexp2(th * L2E) * s;

        int gs;
        if (cnt2 == 1) {
            gs = (int)(t & 0xffffu) - 1;
        } else {
            // argmin over g; sp term is constant across g and drops out.
            // Tagged anchors are union anchors -> no 1e15 branch needed.
            float sc = frcp(1.0f + fexp2(-cf * L2E));
            float xc = ((float)gx + 0.5f) * s;
            float yc = ((float)gy + 0.5f) * s;
            float r = 2.5f * s;
            float bc = 3.402823466e38f;
            gs = 0;
            for (int g2 = 0; g2 < NG; g2++) {
                float bx = gb[g2 * 4], by = gb[g2 * 4 + 1];
                float bw = gb[g2 * 4 + 2], bh = gb[g2 * 4 + 3];
                float iou = iou_cxcywh(bx, by, bw, bh, pcx, pcy, pw, ph);
                float x = base[(5 + gc[g2]) * HW + hw];
                float d = dval_of(x, sc);
                float c = -d - 3.0f * LN2 * flog2(iou + 1e-8f);
                bool ib = (xc > bx - bw * 0.5f) && (bx + bw * 0.5f > xc) &&
                          (yc > by - bh * 0.5f) && (by + bh * 0.5f > yc);
                bool im = (xc > bx - r) && (bx + r > xc) &&
                          (yc > by - r) && (by + r > yc);
                if (!(ib && im)) c += 100000.0f;
                if (c < bc) { bc = c; gs = g2; }
            }
        }
        float miou = iou_cxcywh(gb[gs * 4], gb[gs * 4 + 1], gb[gs * 4 + 2], gb[gs * 4 + 3],
                                pcx, pcy, pw, ph);
        int cid = gc[gs];
        float xcid = base[(5 + cid) * HW + hw];

        // on-demand s0 = sum_c bce0(x_c)
        float s0 = 0.0f;
        const float* cbase = base + 5 * HW + hw;
#pragma unroll
        for (int cc = 0; cc < NC; cc += 20) {
            float x[20];
#pragma unroll
            for (int jj = 0; jj < 20; jj++) x[jj] = cbase[(cc + jj) * HW];
#pragma unroll
            for (int jj = 0; jj < 20; jj++) {
                float u = fexp2(-x[jj] * L2E);
                s0 += x[jj] + LN2 * flog2(1.0f + u);
            }
        }

        lbox += 1.0f - miou * miou;
        lconfc -= cf;
        lcls += s0 - xcid * miou;
        nfg += 1.0f;
    }

    // block reduce the four partials -> one float4 store (no atomics)
    float vals[4] = {lbox, lconfc, lcls, nfg};
    float outv[4];
    for (int i = 0; i < 4; i++) {
        red[tid] = vals[i];
        __syncthreads();
        for (int s2 = 128; s2 > 0; s2 >>= 1) {
            if (tid < s2) red[tid] += red[tid + s2];
            __syncthreads();
        }
        outv[i] = red[0];
        __syncthreads();
    }
    if (tid == 0)
        part3[b * K3_CH + chunk] = make_float4(outv[0], outv[1], outv[2], outv[3]);
}

// ---------- kernel 4: sum partials + final scalar ----------
__global__ __launch_bounds__(256) void k4_final(
    const float* __restrict__ part, const float4* __restrict__ part3, float* __restrict__ out) {
    __shared__ float red[256];
    int tid = threadIdx.x;
    float v = 0.0f;
    for (int i = tid; i < NWAVE; i += 256) v += part[i];
    float4 p = part3[tid];               // exactly K3_BLOCKS = 256 entries
    float vals[5] = {v, p.x, p.y, p.z, p.w};
    float tot[5];
    for (int i = 0; i < 5; i++) {
        red[tid] = vals[i];
        __syncthreads();
        for (int s2 = 128; s2 > 0; s2 >>= 1) {
            if (tid < s2) red[tid] += red[tid + s2];
            __syncthreads();
        }
        tot[i] = red[0];
        __syncthreads();
    }
    if (tid == 0) {
        float nfg = tot[4];
        if (nfg < 1.0f) nfg = 1.0f;
        out[0] = (5.0f * tot[1] + (tot[0] + tot[2]) + tot[3]) / nfg;
    }
}

// ---------- launch ----------
extern "C" void kernel_launch(void* const* d_in, const int* in_sizes, int n_in,
                              void* d_out, int out_size, void* d_ws, size_t ws_size,
                              hipStream_t stream) {
    const float* p8  = (const float*)d_in[0];
    const float* p16 = (const float*)d_in[1];
    const float* p32 = (const float*)d_in[2];
    const float* gtb = (const float*)d_in[3];
    const int*   gtc = (const int*)d_in[4];

    char* w = (char*)d_ws;
    float4* pbox_c = (float4*)w;               w += (size_t)NB * SEG * sizeof(float4);
    float4* rec_c  = (float4*)w;               w += (size_t)NB * SEG * sizeof(float4);
    int* cmp       = (int*)w;                  w += (size_t)NB * SEG * sizeof(int);
    int* cnt       = (int*)w;                  w += (size_t)NB * K1_GX * sizeof(int);
    int* sel       = (int*)w;                  w += (size_t)NB * NG * 10 * sizeof(int);
    int* nsel      = (int*)w;                  w += (size_t)NB * NG * sizeof(int);
    float* part    = (float*)w;                w += (size_t)NWAVE * sizeof(float);
    float4* part3  = (float4*)w;               w += (size_t)K3_BLOCKS * sizeof(float4);

    k1_decode<<<dim3(K1_GX, NB), 256, 0, stream>>>(
        p8, p16, p32, gtb, pbox_c, rec_c, cmp, cnt, part);
    k2_assign<<<NB * NG, 256, 0, stream>>>(gtb, gtc, pbox_c, rec_c, cmp, cnt,
                                           p8, p16, p32, sel, nsel);
    k3_resolve<<<dim3(K3_CH, NB), 256, 0, stream>>>(gtb, gtc, sel, nsel,
                                                    p8, p16, p32, part3);
    k4_final<<<1, 256, 0, stream>>>(part, part3, (float*)d_out);
}